// Round 1
// 138.899 us; speedup vs baseline: 1.0310x; 1.0310x over previous
//
#include <hip/hip_runtime.h>

// Problem constants (from reference setup_inputs)
constexpr int B = 128;
constexpr int A = 1024;
constexpr int M = 6;
constexpr int T = 16;

constexpr float AGENT_THRESH = 0.5f;
constexpr float X_DIS_THRESH = 1.5f;
constexpr float Y_DIS_THRESH = 3.0f;
constexpr float DIS_THRESH_SQ = 9.0f;   // dist > 3.0  <=>  dist^2 > 9.0 (dist >= 0)
constexpr float PEN = 100.0f;

// k1: 4 blocks per batch, 256 threads/block, 1 agent per thread.
// Writes per-block partial mins ws[blockIdx][32] where slot = t*2 + (0=x,1=y).
//
// Reduction strategy: reduce-scatter butterfly. Each exchange step halves the
// number of live slots per lane (32->16->8->4->2->1), so total shuffles per
// thread are 16+8+4+2+1+1 = 32 instead of 6*32 = 192 for a full butterfly.
// After the o=2 step, lane holds the slot (lane>>1)&31; lanes pair-duplicate
// after the final o=1 combine.
__global__ __launch_bounds__(256) void ppcl_k1(
    const float* __restrict__ ego,     // [B, T, 2]
    const float* __restrict__ fut,     // [B, A, M, T, 2]
    const float* __restrict__ score,   // [B, A, M]
    float* __restrict__ ws)            // [gridDim.x, 32]
{
    const int b     = blockIdx.x >> 2;
    const int agent = ((blockIdx.x & 3) << 8) + threadIdx.x;

    // ego for this batch: uniform (blockIdx-derived) address on a const
    // __restrict__ pointer -> scalarizable; avoids 32 ds_read_b32/thread.
    float eg[T * 2];
    {
        const float4* ep = reinterpret_cast<const float4*>(ego + b * (T * 2));
#pragma unroll
        for (int i = 0; i < 8; ++i) {
            float4 q = ep[i];
            eg[4 * i + 0] = q.x;
            eg[4 * i + 1] = q.y;
            eg[4 * i + 2] = q.z;
            eg[4 * i + 3] = q.w;
        }
    }

    // argmax over the 6 mode scores (first-max semantics via strict >)
    // 24 B per agent, 8-byte aligned -> 3x float2
    const float2* sp2 = reinterpret_cast<const float2*>(
        score + ((size_t)b * A + agent) * M);
    float2 s01 = sp2[0], s23 = sp2[1], s45 = sp2[2];
    float best = s01.x;
    int   bm   = 0;
    if (s01.y > best) { best = s01.y; bm = 1; }
    if (s23.x > best) { best = s23.x; bm = 2; }
    if (s23.y > best) { best = s23.y; bm = 3; }
    if (s45.x > best) { best = s45.x; bm = 4; }
    if (s45.y > best) { best = s45.y; bm = 5; }
    const bool lowconf = (best < AGENT_THRESH);

    // best-mode trajectory: 32 contiguous floats, 128B-aligned -> 8x float4
    const float4* tp = reinterpret_cast<const float4*>(
        fut + (((size_t)b * A + agent) * M + bm) * (T * 2));

    float v[T * 2];   // v[2*t] = x_dist, v[2*t+1] = y_dist
#pragma unroll
    for (int i = 0; i < 8; ++i) {
        float4 q = tp[i];
        {
            const int t = 2 * i;
            float dx = eg[2 * t]     - q.x;
            float dy = eg[2 * t + 1] - q.y;
            float d2 = dx * dx + dy * dy;
            float pen = (d2 > DIS_THRESH_SQ || lowconf) ? PEN : 0.0f;
            v[2 * t]     = fabsf(dx) + pen;
            v[2 * t + 1] = fabsf(dy) + pen;
        }
        {
            const int t = 2 * i + 1;
            float dx = eg[2 * t]     - q.z;
            float dy = eg[2 * t + 1] - q.w;
            float d2 = dx * dx + dy * dy;
            float pen = (d2 > DIS_THRESH_SQ || lowconf) ? PEN : 0.0f;
            v[2 * t]     = fabsf(dx) + pen;
            v[2 * t + 1] = fabsf(dy) + pen;
        }
    }

    const int lane = threadIdx.x & 63;

    // Reduce-scatter butterfly over the 64-lane wave.
    // Step (o, n): lanes with (lane & o)==0 keep the low n slots, lanes with
    // (lane & o)!=0 keep the high n slots; each lane sends the half it drops.
#define RS_STEP(o, n)                                              \
    {                                                              \
        const bool hi = (lane & (o)) != 0;                         \
        _Pragma("unroll")                                          \
        for (int i = 0; i < (n); ++i) {                            \
            float send = hi ? v[i] : v[(n) + i];                   \
            float recv = __shfl_xor(send, (o), 64);                \
            float keep = hi ? v[(n) + i] : v[i];                   \
            v[i] = fminf(keep, recv);                              \
        }                                                          \
    }
    RS_STEP(32, 16)
    RS_STEP(16, 8)
    RS_STEP(8, 4)
    RS_STEP(4, 2)
    RS_STEP(2, 1)
#undef RS_STEP
    // lanes 2k and 2k+1 now hold the two halves of slot (lane>>1)&31
    v[0] = fminf(v[0], __shfl_xor(v[0], 1, 64));
    const int slot = (lane >> 1) & 31;

    // cross-wave reduction via 512 B of LDS
    __shared__ float s_red[4][T * 2];
    const int wave = threadIdx.x >> 6;
    if ((lane & 1) == 0) s_red[wave][slot] = v[0];
    __syncthreads();

    if (threadIdx.x < T * 2) {
        float m = fminf(fminf(s_red[0][threadIdx.x], s_red[1][threadIdx.x]),
                        fminf(s_red[2][threadIdx.x], s_red[3][threadIdx.x]));
        ws[(size_t)blockIdx.x * (T * 2) + threadIdx.x] = m;
    }
}

// k2: single 256-thread block. Final min over the 4 partial blocks per batch,
// hinge loss, mask, mean -> scalar.
__global__ __launch_bounds__(256) void ppcl_k2(
    const float* __restrict__ ws,     // [B*4, 32]
    const float* __restrict__ mask,   // [B, T]
    float* __restrict__ out)          // [1]
{
    float acc = 0.0f;
#pragma unroll
    for (int i = 0; i < 16; ++i) {
        const int v   = i * 256 + threadIdx.x;   // 0..4095 = (b, t, xy)
        const int b   = v >> 5;
        const int rem = v & 31;
        const int t   = rem >> 1;
        const int xy  = rem & 1;

        float m = ws[(size_t)(b * 4 + 0) * 32 + rem];
        m = fminf(m, ws[(size_t)(b * 4 + 1) * 32 + rem]);
        m = fminf(m, ws[(size_t)(b * 4 + 2) * 32 + rem]);
        m = fminf(m, ws[(size_t)(b * 4 + 3) * 32 + rem]);

        const float thr  = xy ? Y_DIS_THRESH : X_DIS_THRESH;
        float loss = (m <= thr) ? (thr - m) : 0.0f;
        loss *= mask[b * T + t];
        acc += loss;
    }

    // 64-lane sum reduce
#pragma unroll
    for (int off = 32; off > 0; off >>= 1) acc += __shfl_xor(acc, off, 64);

    __shared__ float s[4];
    const int wave = threadIdx.x >> 6;
    const int lane = threadIdx.x & 63;
    if (lane == 0) s[wave] = acc;
    __syncthreads();
    if (threadIdx.x == 0)
        out[0] = (s[0] + s[1] + s[2] + s[3]) * (1.0f / (B * T * 2));
}

extern "C" void kernel_launch(void* const* d_in, const int* in_sizes, int n_in,
                              void* d_out, int out_size, void* d_ws, size_t ws_size,
                              hipStream_t stream) {
    const float* ego   = (const float*)d_in[0];  // [B, T, 2]
    const float* fut   = (const float*)d_in[1];  // [B, A, M, T, 2]
    const float* score = (const float*)d_in[2];  // [B, A, M]
    const float* mask  = (const float*)d_in[3];  // [B, T]
    float* out = (float*)d_out;
    float* ws  = (float*)d_ws;                   // needs 512*32*4 = 64 KB

    ppcl_k1<<<B * 4, 256, 0, stream>>>(ego, fut, score, ws);
    ppcl_k2<<<1, 256, 0, stream>>>(ws, mask, out);
}